// Round 8
// baseline (330.034 us; speedup 1.0000x reference)
//
#include <hip/hip_runtime.h>
#include <hip/hip_cooperative_groups.h>
#include <stdint.h>

namespace cg = cooperative_groups;

typedef unsigned long long u64;
typedef unsigned int u32;

#define CONF_T 0.9f
#define IOU_T 0.5f
#define TOPK 4096
#define CAP 384            // per-bin segment capacity (expected ~84, max ~140)
#define NB 512
#define NT 256
#define NTOT (NB * NT)

// ---- workspace layout (bytes) ----
#define BINCNT_OFF 0         // u32[4096]       16384
#define VALIDW_OFF 16384     // u64[64]         512
#define NZW_OFF    16896     // u64[64]         512
#define KEEPG_OFF  17408     // u64[64]         512
#define SELBOX_OFF 32768     // float4[4096]    65536
#define SELSC_OFF  98304     // float[4096]     16384
#define SELLM_OFF  114688    // float[40960]    163840
#define MASK_OFF   278528    // u64[4096*64]    2097152
#define BINSEG_OFF 2375680   // u64[4096*384]   12582912

__device__ __forceinline__ int score_bin(float s) {
    u32 b = __float_as_uint(s);
    if (b >= 0x3F800000u) return 0;
    int bin = (int)((0x3F800000u - b) >> 9);
    return bin > 4095 ? 4095 : bin;
}

__global__ void __launch_bounds__(NT) mega(
        const float4* __restrict__ conf4, int N2,
        const float4* __restrict__ loc, const float4* __restrict__ priors,
        const float* __restrict__ landm,
        u32* __restrict__ binCnt, u64* __restrict__ binseg,
        float4* __restrict__ selbox, float* __restrict__ selscore,
        float* __restrict__ sellm,
        u64* __restrict__ mask, u64* __restrict__ validw, u64* __restrict__ nzw,
        u64* __restrict__ keepg, float* __restrict__ out) {
    cg::grid_group grid = cg::this_grid();
    __shared__ alignas(16) char smem[65536];
    int t = threadIdx.x, b = blockIdx.x;
    int gtid = b * NT + t;

    // ---- P0: zero counters ----
    if (gtid < 4096) binCnt[gtid] = 0u;
    if (gtid < 64) { validw[gtid] = 0ull; nzw[gtid] = 0ull; }
    grid.sync();

    // ---- P1: conf scan -> direct per-bin scatter (binCnt doubles as hist) ----
    for (int i = gtid; i < N2; i += NTOT) {
        float4 v = conf4[i];
        if (v.y > CONF_T) {
            int bb = score_bin(v.y);
            u32 p = atomicAdd(&binCnt[bb], 1u);
            if (p < CAP)
                binseg[(size_t)bb * CAP + p] =
                    ((u64)__float_as_uint(v.y) << 32) | (u64)(~(u32)(2 * i));
        }
        if (v.w > CONF_T) {
            int bb = score_bin(v.w);
            u32 p = atomicAdd(&binCnt[bb], 1u);
            if (p < CAP)
                binseg[(size_t)bb * CAP + p] =
                    ((u64)__float_as_uint(v.w) << 32) | (u64)(~(u32)(2 * i + 1));
        }
    }
    grid.sync();

    // ---- P2: rank + decode + scatter (blocks 0..31; redundant LDS prefix) ----
    if (b < 32) {
        u32* pref_s = (u32*)smem;            // [4097]
        u32* parts  = (u32*)(smem + 16400);  // [256]
        u32* m_sh   = (u32*)(smem + 17424);  // [1]
        u32 h[16];
        u32 sum = 0;
        #pragma unroll
        for (int i = 0; i < 16; i++) {
            u32 c = binCnt[t * 16 + i];
            h[i] = c > CAP ? CAP : c;
            sum += h[i];
        }
        parts[t] = sum;
        if (t == 0) *m_sh = 0u;
        __syncthreads();
        for (int d = 1; d < 256; d <<= 1) {
            u32 add = (t >= d) ? parts[t - d] : 0u;
            __syncthreads();
            parts[t] += add;
            __syncthreads();
        }
        u32 incl = parts[t];
        u32 excl = incl - sum;
        u32 run = excl;
        #pragma unroll
        for (int i = 0; i < 16; i++) { pref_s[t * 16 + i] = run; run += h[i]; }
        if (t == 255) pref_s[4096] = run;
        __syncthreads();
        u32 total = pref_s[4096];
        u32 target = total < TOPK ? total : TOPK;
        if (total > 0 && excl < target && incl >= target) {
            u32 r2 = excl;
            #pragma unroll
            for (int i = 0; i < 16; i++) {
                r2 += h[i];
                if (r2 >= target) { *m_sh = r2; break; }
            }
        }
        __syncthreads();
        u32 M = *m_sh;
        u32 p = (u32)gtid;   // blocks 0..31 -> p in [0, 8192)
        if (p >= M) {
            if (p < TOPK) {   // zero-pad unused ranks
                selbox[p] = make_float4(0.f, 0.f, 0.f, 0.f);
                selscore[p] = 0.f;
                #pragma unroll
                for (int q = 0; q < 10; q++) sellm[(size_t)p * 10 + q] = 0.f;
            }
        } else {
            int lo = 0, hi = 4095;   // largest bin with pref_s[bin] <= p
            while (lo < hi) {
                int mid = (lo + hi + 1) >> 1;
                if (pref_s[mid] <= p) lo = mid; else hi = mid - 1;
            }
            u32 st = pref_s[lo];
            u32 cnt = pref_s[lo + 1] - st;
            const u64* seg = binseg + (size_t)lo * CAP;
            u64 key = seg[p - st];
            u32 rank = st;
            for (u32 j = 0; j < cnt; j++) rank += (seg[j] > key) ? 1u : 0u;
            if (rank < TOPK) {
                u32 idx = ~(u32)key;
                float sc = __uint_as_float((u32)(key >> 32));
                float4 L = loc[idx];
                float4 P = priors[idx];
                float cx = P.x + L.x * 0.1f * P.z;
                float cy = P.y + L.y * 0.1f * P.w;
                float wx = P.z * expf(L.z * 0.2f);
                float wy = P.w * expf(L.w * 0.2f);
                float4 bx;
                bx.x = (cx - 0.5f * wx) * 8192.f;
                bx.y = (cy - 0.5f * wy) * 8192.f;
                bx.z = (cx + 0.5f * wx) * 8192.f;
                bx.w = (cy + 0.5f * wy) * 8192.f;
                selbox[rank] = bx;
                selscore[rank] = sc;
                const float* lmr = landm + (size_t)idx * 10;
                float* lmo = sellm + (size_t)rank * 10;
                #pragma unroll
                for (int q = 0; q < 5; q++) {
                    float lx = lmr[2 * q], ly = lmr[2 * q + 1];
                    lmo[2 * q]     = (P.x + lx * 0.1f * P.z) * 8192.f;
                    lmo[2 * q + 1] = (P.y + ly * 0.1f * P.w) * 8192.f;
                }
            }
        }
    }
    grid.sync();

    // ---- P3: mask matrix (8 rows/block, 2 rows/wave, conflict-free) ----
    {
        float4* sb = (float4*)smem;
        for (int i = t; i < TOPK; i += NT) sb[i] = selbox[i];
        __syncthreads();
        int wv = t >> 6, lane = t & 63;
        int rbase = b * 8 + wv * 2;
        float4 r0 = sb[rbase], r1 = sb[rbase + 1];
        float a0 = fmaxf(r0.z - r0.x, 0.f) * fmaxf(r0.w - r0.y, 0.f);
        float a1 = fmaxf(r1.z - r1.x, 0.f) * fmaxf(r1.w - r1.y, 0.f);
        u64 w0 = 0, w1 = 0;
        for (int w = 0; w < 64; w++) {
            if (w * 64 + 63 <= rbase) continue;
            int j = w * 64 + lane;
            float4 bj = sb[j];
            float aj = fmaxf(bj.z - bj.x, 0.f) * fmaxf(bj.w - bj.y, 0.f);
            #define IOU_BIT(rr, aa, row) ({ \
                float lx = fmaxf(rr.x, bj.x), ly = fmaxf(rr.y, bj.y); \
                float rx = fminf(rr.z, bj.z), ry = fminf(rr.w, bj.w); \
                float inter = fmaxf(rx - lx, 0.f) * fmaxf(ry - ly, 0.f); \
                float iou = inter / (aa + aj - inter + 1e-12f); \
                (j > (row)) && (iou > IOU_T); })
            u64 bb0 = __ballot(IOU_BIT(r0, a0, rbase + 0));
            u64 bb1 = __ballot(IOU_BIT(r1, a1, rbase + 1));
            #undef IOU_BIT
            if (lane == w) { w0 = bb0; w1 = bb1; }
        }
        mask[(size_t)(rbase + 0) * 64 + lane] = w0;
        mask[(size_t)(rbase + 1) * 64 + lane] = w1;
        u64 nz0 = __ballot(w0 != 0ull), nz1 = __ballot(w1 != 0ull);
        u64 vb = __ballot(lane < 2 && selscore[rbase + lane] > CONF_T);  // bits 0..1
        if (lane == 0) {
            int g = rbase >> 6;
            int sh = rbase & 63;
            u64 nzb = (nz0 ? 1ull : 0) | (nz1 ? 2ull : 0);
            if (vb)  atomicOr(&validw[g], vb << sh);
            if (nzb) atomicOr(&nzw[g], nzb << sh);
        }
    }
    grid.sync();

    // ---- P4: serial greedy NMS (block 0, wave 0) ----
    if (b == 0 && t < 64) {
        u64 vw = validw[t];
        u64 nzv = nzw[t];
        u64 sup = 0ull, keepw = 0ull;
        for (int g = 0; g < 64; g++) {
            u64 cur = __shfl(sup, g);
            u64 validg = __shfl(vw, g);
            u64 nzg = __shfl(nzv, g);
            u64 alive = (~cur) & validg;
            if (nzg) {
                u64 intra = mask[(size_t)(g * 64 + t) * 64 + g];
                u64 rem = nzg;
                while (rem) {
                    int bb = __ffsll((long long)rem) - 1;
                    rem &= rem - 1;
                    if ((alive >> bb) & 1ull) {
                        u64 rowb = __shfl(intra, bb);
                        alive &= ~rowb;
                    }
                }
            }
            if (t == g) keepw = alive;
            u64 srem = alive & nzg;
            const u64* mb = mask + (size_t)(g * 64) * 64 + t;
            while (srem) {
                int i0, i1 = -1, i2 = -1, i3 = -1, i4 = -1, i5 = -1, i6 = -1, i7 = -1;
                i0 = __ffsll((long long)srem) - 1; srem &= srem - 1;
                if (srem) { i1 = __ffsll((long long)srem) - 1; srem &= srem - 1;
                if (srem) { i2 = __ffsll((long long)srem) - 1; srem &= srem - 1;
                if (srem) { i3 = __ffsll((long long)srem) - 1; srem &= srem - 1;
                if (srem) { i4 = __ffsll((long long)srem) - 1; srem &= srem - 1;
                if (srem) { i5 = __ffsll((long long)srem) - 1; srem &= srem - 1;
                if (srem) { i6 = __ffsll((long long)srem) - 1; srem &= srem - 1;
                if (srem) { i7 = __ffsll((long long)srem) - 1; srem &= srem - 1; } } } } } } }
                u64 a0 = mb[(size_t)i0 * 64];
                u64 a1 = (i1 >= 0) ? mb[(size_t)i1 * 64] : 0ull;
                u64 a2 = (i2 >= 0) ? mb[(size_t)i2 * 64] : 0ull;
                u64 a3 = (i3 >= 0) ? mb[(size_t)i3 * 64] : 0ull;
                u64 a4 = (i4 >= 0) ? mb[(size_t)i4 * 64] : 0ull;
                u64 a5 = (i5 >= 0) ? mb[(size_t)i5 * 64] : 0ull;
                u64 a6 = (i6 >= 0) ? mb[(size_t)i6 * 64] : 0ull;
                u64 a7 = (i7 >= 0) ? mb[(size_t)i7 * 64] : 0ull;
                sup |= (a0 | a1) | (a2 | a3) | ((a4 | a5) | (a6 | a7));
            }
        }
        keepg[t] = keepw;
    }
    grid.sync();

    // ---- P5: masked output write (one thread per element) ----
    if (gtid < TOPK * 15) {
        int row = gtid / 15;
        int col = gtid - row * 15;
        bool kp = (keepg[row >> 6] >> (row & 63)) & 1ull;
        const float* sbf = (const float*)selbox;
        float val;
        if (col < 4)       val = sbf[row * 4 + col];
        else if (col == 4) val = selscore[row];
        else               val = sellm[(size_t)row * 10 + (col - 5)];
        out[gtid] = kp ? val : 0.f;
    }
}

extern "C" void kernel_launch(void* const* d_in, const int* in_sizes, int n_in,
                              void* d_out, int out_size, void* d_ws, size_t ws_size,
                              hipStream_t stream) {
    const float4* loc    = (const float4*)d_in[0];
    const float4* conf4  = (const float4*)d_in[1];
    const float*  landm  = (const float*)d_in[2];
    const float4* priors = (const float4*)d_in[3];
    float* out = (float*)d_out;
    int N = in_sizes[1] / 2;
    int N2 = N / 2;   // float4 elements (2 anchors each)

    char* ws = (char*)d_ws;
    u32* binCnt   = (u32*)(ws + BINCNT_OFF);
    u64* validw   = (u64*)(ws + VALIDW_OFF);
    u64* nzw      = (u64*)(ws + NZW_OFF);
    u64* keepg    = (u64*)(ws + KEEPG_OFF);
    float4* selbox = (float4*)(ws + SELBOX_OFF);
    float* selsc   = (float*)(ws + SELSC_OFF);
    float* sellm   = (float*)(ws + SELLM_OFF);
    u64* maskp    = (u64*)(ws + MASK_OFF);
    u64* binseg   = (u64*)(ws + BINSEG_OFF);

    void* args[] = { &conf4, &N2, &loc, &priors, &landm,
                     &binCnt, &binseg, &selbox, &selsc, &sellm,
                     &maskp, &validw, &nzw, &keepg, &out };
    hipLaunchCooperativeKernel(reinterpret_cast<void*>(mega),
                               dim3(NB), dim3(NT), args, 0, stream);
}

// Round 9
// 105.975 us; speedup vs baseline: 3.1143x; 3.1143x over previous
//
#include <hip/hip_runtime.h>
#include <stdint.h>

typedef unsigned long long u64;
typedef unsigned int u32;

#define CONF_T 0.9f
#define IOU_T 0.5f
#define TOPK 4096
#define CAP 384            // per-bin segment capacity (expected ~84, max ~140)
#define MASKBLK 256

// ---- workspace layout (bytes) ----
#define BINCNT_OFF 0         // u32[4096]       16384
#define VALIDW_OFF 16384     // u64[64]         512
#define NZW_OFF    16896     // u64[64]         512
#define TICKET_OFF 17408     // u32[16]
#define SELBOX_OFF 32768     // float4[4096]    65536
#define SELSC_OFF  98304     // float[4096]     16384
#define SELLM_OFF  114688    // float[40960]    163840
#define MASK_OFF   278528    // u64[4096*64]    2097152
#define BINSEG_OFF 2375680   // u64[4096*384]   12582912

__device__ __forceinline__ int score_bin(float s) {
    u32 b = __float_as_uint(s);
    if (b >= 0x3F800000u) return 0;
    int bin = (int)((0x3F800000u - b) >> 9);
    return bin > 4095 ? 4095 : bin;
}

// K0: zero binCnt + validw/nzw + ticket
__global__ void k_zero(u32* __restrict__ binCnt, u64* __restrict__ validw,
                       u64* __restrict__ nzw, u32* __restrict__ ticket) {
    int i = blockIdx.x * 256 + threadIdx.x;
    binCnt[i] = 0u;
    if (i < 64) { validw[i] = 0ull; nzw[i] = 0ull; }
    if (i < 16) ticket[i] = 0u;
}

// K1: single conf scan, candidates scattered directly into per-bin segments.
__global__ void __launch_bounds__(256) k_compact(
        const float4* __restrict__ conf4, int N2,
        u32* __restrict__ binCnt, u64* __restrict__ binseg) {
    int stride = gridDim.x * 256;
    for (int i = blockIdx.x * 256 + threadIdx.x; i < N2; i += stride) {
        float4 v = conf4[i];
        if (v.y > CONF_T) {
            int b = score_bin(v.y);
            u32 p = atomicAdd(&binCnt[b], 1u);
            if (p < CAP)
                binseg[(size_t)b * CAP + p] =
                    ((u64)__float_as_uint(v.y) << 32) | (u64)(~(u32)(2 * i));
        }
        if (v.w > CONF_T) {
            int b = score_bin(v.w);
            u32 p = atomicAdd(&binCnt[b], 1u);
            if (p < CAP)
                binseg[(size_t)b * CAP + p] =
                    ((u64)__float_as_uint(v.w) << 32) | (u64)(~(u32)(2 * i + 1));
        }
    }
}

// K2: per-block redundant prefix scan of binCnt in LDS, then exact rank within
// bin + decode + scatter to rank position; threads beyond M zero-pad.
__global__ void __launch_bounds__(256) k_rankscan(
        const float4* __restrict__ loc, const float4* __restrict__ priors,
        const float* __restrict__ landm, const u32* __restrict__ binCnt,
        const u64* __restrict__ binseg,
        float4* __restrict__ selbox, float* __restrict__ selscore,
        float* __restrict__ sellm) {
    __shared__ u32 pref_s[4097];
    __shared__ u32 parts[256];
    __shared__ u32 m_sh;
    int t = threadIdx.x;
    u32 h[16];
    u32 sum = 0;
    #pragma unroll
    for (int i = 0; i < 16; i++) {
        u32 c = binCnt[t * 16 + i];
        h[i] = c > CAP ? CAP : c;
        sum += h[i];
    }
    parts[t] = sum;
    if (t == 0) m_sh = 0u;
    __syncthreads();
    for (int d = 1; d < 256; d <<= 1) {
        u32 add = (t >= d) ? parts[t - d] : 0u;
        __syncthreads();
        parts[t] += add;
        __syncthreads();
    }
    u32 incl = parts[t];
    u32 excl = incl - sum;
    u32 run = excl;
    #pragma unroll
    for (int i = 0; i < 16; i++) { pref_s[t * 16 + i] = run; run += h[i]; }
    if (t == 255) pref_s[4096] = run;   // total
    __syncthreads();
    u32 total = pref_s[4096];
    u32 target = total < TOPK ? total : TOPK;
    if (total > 0 && excl < target && incl >= target) {
        u32 r2 = excl;
        #pragma unroll
        for (int i = 0; i < 16; i++) {
            r2 += h[i];
            if (r2 >= target) { m_sh = r2; break; }
        }
    }
    __syncthreads();
    u32 M = m_sh;
    u32 p = blockIdx.x * 256 + t;
    if (p >= M) {
        if (p < TOPK) {   // zero-pad unused ranks
            selbox[p] = make_float4(0.f, 0.f, 0.f, 0.f);
            selscore[p] = 0.f;
            #pragma unroll
            for (int q = 0; q < 10; q++) sellm[(size_t)p * 10 + q] = 0.f;
        }
        return;
    }
    int lo = 0, hi = 4095;   // largest bin with pref_s[bin] <= p
    while (lo < hi) {
        int mid = (lo + hi + 1) >> 1;
        if (pref_s[mid] <= p) lo = mid; else hi = mid - 1;
    }
    u32 st = pref_s[lo];
    u32 cnt = pref_s[lo + 1] - st;
    const u64* seg = binseg + (size_t)lo * CAP;
    u64 key = seg[p - st];
    u32 rank = st;
    for (u32 j = 0; j < cnt; j++) rank += (seg[j] > key) ? 1u : 0u;
    if (rank >= TOPK) return;
    u32 idx = ~(u32)key;
    float sc = __uint_as_float((u32)(key >> 32));
    float4 L = loc[idx];
    float4 P = priors[idx];
    float cx = P.x + L.x * 0.1f * P.z;
    float cy = P.y + L.y * 0.1f * P.w;
    float wx = P.z * expf(L.z * 0.2f);
    float wy = P.w * expf(L.w * 0.2f);
    float4 bx;
    bx.x = (cx - 0.5f * wx) * 8192.f;
    bx.y = (cy - 0.5f * wy) * 8192.f;
    bx.z = (cx + 0.5f * wx) * 8192.f;
    bx.w = (cy + 0.5f * wy) * 8192.f;
    selbox[rank] = bx;
    selscore[rank] = sc;
    const float* lmr = landm + (size_t)idx * 10;
    float* lmo = sellm + (size_t)rank * 10;
    #pragma unroll
    for (int q = 0; q < 5; q++) {
        float lx = lmr[2 * q], ly = lmr[2 * q + 1];
        lmo[2 * q]     = (P.x + lx * 0.1f * P.z) * 8192.f;
        lmo[2 * q + 1] = (P.y + ly * 0.1f * P.w) * 8192.f;
    }
}

// K3: mask matrix + ballots + unconditional out write for this block's 16 rows,
// then last-block (ticket) runs serial greedy NMS and zeroes non-kept rows.
__global__ void __launch_bounds__(256) k_maskfin(
        const float4* __restrict__ selbox, const float* __restrict__ selscore,
        const float* __restrict__ sellm,
        u64* __restrict__ mask, u64* __restrict__ validw, u64* __restrict__ nzw,
        u32* __restrict__ ticket, float* __restrict__ out) {
    __shared__ float4 sb[TOPK];   // 64 KB
    __shared__ u64 keep_s[64];
    __shared__ u32 last_sh;
    int t = threadIdx.x, b = blockIdx.x;
    for (int i = t; i < TOPK; i += 256) sb[i] = selbox[i];
    __syncthreads();
    int wv = t >> 6, lane = t & 63;
    int rbase = b * 16 + wv * 4;
    float4 r0 = sb[rbase], r1 = sb[rbase + 1], r2 = sb[rbase + 2], r3 = sb[rbase + 3];
    float a0 = fmaxf(r0.z - r0.x, 0.f) * fmaxf(r0.w - r0.y, 0.f);
    float a1 = fmaxf(r1.z - r1.x, 0.f) * fmaxf(r1.w - r1.y, 0.f);
    float a2 = fmaxf(r2.z - r2.x, 0.f) * fmaxf(r2.w - r2.y, 0.f);
    float a3 = fmaxf(r3.z - r3.x, 0.f) * fmaxf(r3.w - r3.y, 0.f);
    u64 w0 = 0, w1 = 0, w2 = 0, w3 = 0;
    for (int w = 0; w < 64; w++) {
        if (w * 64 + 63 <= rbase) continue;
        int j = w * 64 + lane;
        float4 bj = sb[j];
        float aj = fmaxf(bj.z - bj.x, 0.f) * fmaxf(bj.w - bj.y, 0.f);
        #define IOU_BIT(rr, aa, row) ({ \
            float lx = fmaxf(rr.x, bj.x), ly = fmaxf(rr.y, bj.y); \
            float rx = fminf(rr.z, bj.z), ry = fminf(rr.w, bj.w); \
            float inter = fmaxf(rx - lx, 0.f) * fmaxf(ry - ly, 0.f); \
            float iou = inter / (aa + aj - inter + 1e-12f); \
            (j > (row)) && (iou > IOU_T); })
        u64 bb0 = __ballot(IOU_BIT(r0, a0, rbase + 0));
        u64 bb1 = __ballot(IOU_BIT(r1, a1, rbase + 1));
        u64 bb2 = __ballot(IOU_BIT(r2, a2, rbase + 2));
        u64 bb3 = __ballot(IOU_BIT(r3, a3, rbase + 3));
        #undef IOU_BIT
        if (lane == w) { w0 = bb0; w1 = bb1; w2 = bb2; w3 = bb3; }
    }
    mask[(size_t)(rbase + 0) * 64 + lane] = w0;
    mask[(size_t)(rbase + 1) * 64 + lane] = w1;
    mask[(size_t)(rbase + 2) * 64 + lane] = w2;
    mask[(size_t)(rbase + 3) * 64 + lane] = w3;
    u64 nz0 = __ballot(w0 != 0ull), nz1 = __ballot(w1 != 0ull);
    u64 nz2 = __ballot(w2 != 0ull), nz3 = __ballot(w3 != 0ull);
    u64 vb = __ballot(lane < 4 && selscore[rbase + lane] > CONF_T);  // bits 0..3
    if (lane == 0) {
        int g = rbase >> 6;
        int sh = rbase & 63;
        u64 nzb = (nz0 ? 1ull : 0) | (nz1 ? 2ull : 0) | (nz2 ? 4ull : 0) | (nz3 ? 8ull : 0);
        if (vb)  atomicOr(&validw[g], vb << sh);
        if (nzb) atomicOr(&nzw[g], nzb << sh);
    }
    // unconditional output write for this block's 16 rows
    if (t < 240) {
        int row = b * 16 + t / 15;
        int col = t - (t / 15) * 15;
        const float* sbf = (const float*)selbox;
        float val;
        if (col < 4)       val = sbf[row * 4 + col];
        else if (col == 4) val = selscore[row];
        else               val = sellm[(size_t)row * 10 + (col - 5)];
        out[(size_t)row * 15 + col] = val;
    }
    // ---- last-block fusion: release, ticket, last block does NMS + zeroing ----
    __threadfence();
    __syncthreads();
    if (t == 0) {
        u32 r = atomicAdd(ticket, 1u);
        last_sh = (r == (u32)(MASKBLK - 1)) ? 1u : 0u;
    }
    __syncthreads();
    if (!last_sh) return;
    __threadfence();   // acquire: see all blocks' mask/validw/nzw writes
    if (t < 64) {
        u64 vw = validw[t];
        u64 nzv = nzw[t];
        u64 sup = 0ull, keepw = 0ull;
        for (int g = 0; g < 64; g++) {
            u64 cur = __shfl(sup, g);
            u64 validg = __shfl(vw, g);
            u64 nzg = __shfl(nzv, g);
            u64 alive = (~cur) & validg;
            if (nzg) {
                u64 intra = mask[(size_t)(g * 64 + t) * 64 + g];
                u64 rem = nzg;
                while (rem) {
                    int bb = __ffsll((long long)rem) - 1;
                    rem &= rem - 1;
                    if ((alive >> bb) & 1ull) {
                        u64 rowb = __shfl(intra, bb);
                        alive &= ~rowb;
                    }
                }
            }
            if (t == g) keepw = alive;
            u64 srem = alive & nzg;
            const u64* mb = mask + (size_t)(g * 64) * 64 + t;
            while (srem) {
                int i0, i1 = -1, i2 = -1, i3 = -1, i4 = -1, i5 = -1, i6 = -1, i7 = -1;
                i0 = __ffsll((long long)srem) - 1; srem &= srem - 1;
                if (srem) { i1 = __ffsll((long long)srem) - 1; srem &= srem - 1;
                if (srem) { i2 = __ffsll((long long)srem) - 1; srem &= srem - 1;
                if (srem) { i3 = __ffsll((long long)srem) - 1; srem &= srem - 1;
                if (srem) { i4 = __ffsll((long long)srem) - 1; srem &= srem - 1;
                if (srem) { i5 = __ffsll((long long)srem) - 1; srem &= srem - 1;
                if (srem) { i6 = __ffsll((long long)srem) - 1; srem &= srem - 1;
                if (srem) { i7 = __ffsll((long long)srem) - 1; srem &= srem - 1; } } } } } } }
                u64 a0 = mb[(size_t)i0 * 64];
                u64 a1 = (i1 >= 0) ? mb[(size_t)i1 * 64] : 0ull;
                u64 a2 = (i2 >= 0) ? mb[(size_t)i2 * 64] : 0ull;
                u64 a3 = (i3 >= 0) ? mb[(size_t)i3 * 64] : 0ull;
                u64 a4 = (i4 >= 0) ? mb[(size_t)i4 * 64] : 0ull;
                u64 a5 = (i5 >= 0) ? mb[(size_t)i5 * 64] : 0ull;
                u64 a6 = (i6 >= 0) ? mb[(size_t)i6 * 64] : 0ull;
                u64 a7 = (i7 >= 0) ? mb[(size_t)i7 * 64] : 0ull;
                sup |= (a0 | a1) | (a2 | a3) | ((a4 | a5) | (a6 | a7));
            }
        }
        keep_s[t] = keepw;
    }
    __syncthreads();
    for (int r = t; r < TOPK; r += 256) {
        if (!((keep_s[r >> 6] >> (r & 63)) & 1ull)) {
            float* o = out + (size_t)r * 15;
            #pragma unroll
            for (int q = 0; q < 15; q++) o[q] = 0.f;
        }
    }
}

extern "C" void kernel_launch(void* const* d_in, const int* in_sizes, int n_in,
                              void* d_out, int out_size, void* d_ws, size_t ws_size,
                              hipStream_t stream) {
    const float4* loc    = (const float4*)d_in[0];
    const float4* conf4  = (const float4*)d_in[1];
    const float*  landm  = (const float*)d_in[2];
    const float4* priors = (const float4*)d_in[3];
    float* out = (float*)d_out;
    int N = in_sizes[1] / 2;
    int N2 = N / 2;   // float4 elements (2 anchors each)

    char* ws = (char*)d_ws;
    u32* binCnt   = (u32*)(ws + BINCNT_OFF);
    u64* validw   = (u64*)(ws + VALIDW_OFF);
    u64* nzw      = (u64*)(ws + NZW_OFF);
    u32* ticket   = (u32*)(ws + TICKET_OFF);
    float4* selbox = (float4*)(ws + SELBOX_OFF);
    float* selsc   = (float*)(ws + SELSC_OFF);
    float* sellm   = (float*)(ws + SELLM_OFF);
    u64* maskp    = (u64*)(ws + MASK_OFF);
    u64* binseg   = (u64*)(ws + BINSEG_OFF);

    k_zero<<<16, 256, 0, stream>>>(binCnt, validw, nzw, ticket);
    k_compact<<<1024, 256, 0, stream>>>(conf4, N2, binCnt, binseg);
    k_rankscan<<<32, 256, 0, stream>>>(loc, priors, landm, binCnt, binseg,
                                       selbox, selsc, sellm);
    k_maskfin<<<MASKBLK, 256, 0, stream>>>(selbox, selsc, sellm, maskp,
                                           validw, nzw, ticket, out);
}